// Round 1
// baseline (471.606 us; speedup 1.0000x reference)
//
#include <hip/hip_runtime.h>
#include <cstdint>

#define EMB 2048
#define NH 16
#define HD 128
#define BB 32
#define TT 16
#define SC 8192
#define ST 8208
#define NS 8
#define QK_SCALE 0.08838834764831845f

typedef __attribute__((ext_vector_type(8))) short short8;
typedef __attribute__((ext_vector_type(4))) float f32x4;

__device__ __forceinline__ ushort f2bf(float f) {
  union { float f; uint32_t u; } v; v.f = f;
  uint32_t u = v.u;
  return (ushort)((u + 0x7FFFu + ((u >> 16) & 1u)) >> 16);
}

// async global->LDS, 16B per lane; LDS dest = wave-uniform base + lane*16
typedef __attribute__((address_space(1))) void gas_t;
typedef __attribute__((address_space(3))) void las_t;
__device__ __forceinline__ void gload16(const void* g, void* l) {
  __builtin_amdgcn_global_load_lds((gas_t*)g, (las_t*)l, 16, 0, 0);
}

// ---------------------------------------------------------------- prepack
// fp32 -> bf16 casts: x, Wq|Wk|Wv packed [2304][2048], Wo, bias concat (f32)
__global__ __launch_bounds__(256) void prepack(
    const float* __restrict__ x, const float* __restrict__ Wq,
    const float* __restrict__ Wk, const float* __restrict__ Wv,
    const float* __restrict__ Wo, const float* __restrict__ bq,
    const float* __restrict__ bk, const float* __restrict__ bv,
    ushort* __restrict__ xbf, ushort* __restrict__ wqkv,
    ushort* __restrict__ wobf, float* __restrict__ biasq) {
  const int B0 = 262144;            // x float4s
  const int B1 = B0 + 1048576;      // Wq
  const int B2 = B1 + 65536;        // Wk
  const int B3 = B2 + 65536;        // Wv
  const int B4 = B3 + 1048576;      // Wo
  const int B5 = B4 + 576;          // bias
  int stride = gridDim.x * blockDim.x;
  for (int i = blockIdx.x * blockDim.x + threadIdx.x; i < B5; i += stride) {
    const float* src; ushort* dst;
    if (i < B0)      { src = x  + (size_t)i * 4;        dst = xbf  + (size_t)i * 4; }
    else if (i < B1) { src = Wq + (size_t)(i - B0) * 4; dst = wqkv + (size_t)(i - B0) * 4; }
    else if (i < B2) { src = Wk + (size_t)(i - B1) * 4; dst = wqkv + 4194304 + (size_t)(i - B1) * 4; }
    else if (i < B3) { src = Wv + (size_t)(i - B2) * 4; dst = wqkv + 4456448 + (size_t)(i - B2) * 4; }
    else if (i < B4) { src = Wo + (size_t)(i - B3) * 4; dst = wobf + (size_t)(i - B3) * 4; }
    else {
      int j = i - B4;
      const float* bs = (j < 512) ? bq + j * 4 : (j < 544) ? bk + (j - 512) * 4 : bv + (j - 544) * 4;
      float4 f = *(const float4*)bs;
      *(float4*)(biasq + j * 4) = f;
      continue;
    }
    float4 f = *(const float4*)src;
    ushort4 o4;
    o4.x = f2bf(f.x); o4.y = f2bf(f.y); o4.z = f2bf(f.z); o4.w = f2bf(f.w);
    *(ushort4*)dst = o4;
  }
}

// ---------------------------------------------------------------- GEMM (NT)
// C[M,N] = A[M,K] * B[N,K]^T + bias ; optional scale on cols < scaleLim.
// M = 512 fixed (Mt=8, BM=64), BN=128, BK=64. 4 waves (2x2), wave = 32x64.
// LDS linear + XOR-swizzled global source (m173) so frag ds_read_b128 is ~2-way.
__global__ __launch_bounds__(256) void gemm_bt(
    const ushort* __restrict__ A, const ushort* __restrict__ B,
    const float* __restrict__ bias, float* __restrict__ outF,
    ushort* __restrict__ outB, int N, int K, float scale, int scaleLim) {
  __shared__ ushort As[64 * 64];
  __shared__ ushort Bs[128 * 64];
  int tid = threadIdx.x, lane = tid & 63, wid = tid >> 6;
  int wm = wid >> 1, wn = wid & 1;
  int nwg = gridDim.x, bid = blockIdx.x;
  int sw = (bid & 7) * (nwg >> 3) + (bid >> 3);   // bijective XCD swizzle (nwg%8==0)
  const int Mt = 8;
  int nt = sw / Mt, mt = sw % Mt;                 // consecutive sw share the B panel
  int m0 = mt * 64, n0 = nt * 128;

  f32x4 acc[2][4];
#pragma unroll
  for (int mf = 0; mf < 2; ++mf)
#pragma unroll
    for (int nf = 0; nf < 4; ++nf) acc[mf][nf] = (f32x4){0.f, 0.f, 0.f, 0.f};

  for (int kt = 0; kt < K / 64; ++kt) {
    int kb = kt * 64;
#pragma unroll
    for (int p = 0; p < 2; ++p) {                 // A: 8KB = 8 chunks of 1KB
      int c = wid * 2 + p;
      int row = c * 8 + (lane >> 3);
      int gg = (lane & 7) ^ (row & 7);
      gload16(A + (size_t)(m0 + row) * K + kb + gg * 8, &As[c * 512]);
    }
#pragma unroll
    for (int p = 0; p < 4; ++p) {                 // B: 16KB = 16 chunks
      int c = wid * 4 + p;
      int row = c * 8 + (lane >> 3);
      int gg = (lane & 7) ^ (row & 7);
      gload16(B + (size_t)(n0 + row) * K + kb + gg * 8, &Bs[c * 512]);
    }
    __syncthreads();
#pragma unroll
    for (int kk = 0; kk < 2; ++kk) {
      short8 af[2], bf4[4];
#pragma unroll
      for (int mf = 0; mf < 2; ++mf) {
        int r = wm * 32 + mf * 16 + (lane & 15);
        int gg = (kk * 4 + (lane >> 4)) ^ (r & 7);
        af[mf] = *(const short8*)&As[r * 64 + gg * 8];
      }
#pragma unroll
      for (int nf = 0; nf < 4; ++nf) {
        int r = wn * 64 + nf * 16 + (lane & 15);
        int gg = (kk * 4 + (lane >> 4)) ^ (r & 7);
        bf4[nf] = *(const short8*)&Bs[r * 64 + gg * 8];
      }
#pragma unroll
      for (int mf = 0; mf < 2; ++mf)
#pragma unroll
        for (int nf = 0; nf < 4; ++nf)
          acc[mf][nf] = __builtin_amdgcn_mfma_f32_16x16x32_bf16(af[mf], bf4[nf], acc[mf][nf], 0, 0, 0);
    }
    __syncthreads();
  }
#pragma unroll
  for (int mf = 0; mf < 2; ++mf)
#pragma unroll
    for (int nf = 0; nf < 4; ++nf)
#pragma unroll
      for (int r = 0; r < 4; ++r) {
        int gr = m0 + wm * 32 + mf * 16 + (lane >> 4) * 4 + r;
        int gc = n0 + wn * 64 + nf * 16 + (lane & 15);
        float v = acc[mf][nf][r] + bias[gc];
        if (gc < scaleLim) v *= scale;            // fold 1/sqrt(hd) into Q cols
        if (outB) outB[(size_t)gr * N + gc] = f2bf(v);
        else      outF[(size_t)gr * N + gc] = v;
      }
}

// ---------------------------------------------------------------- attention partials
// grid (NS, B); block 512 = 8 waves, wave owns 32 q-rows (row = h*16+t).
// Flash-decoding: chunk c covers s in [c*1024, min((c+1)*1024, 8208)).
__global__ __launch_bounds__(512) void attn_part(
    const float* __restrict__ Kc, const float* __restrict__ Vc,
    const ushort* __restrict__ Y, float* __restrict__ Op, float* __restrict__ ML) {
  __shared__ ushort Klds[64 * 136];     // [s][k] pad 8  -> 2-way frag reads
  __shared__ ushort Vt[128 * 72];       // [d][s] pad 8  (transposed V)
  __shared__ ushort Plds[8][32 * 40];   // per-wave P half-tile [32][32+8]
  int tid = threadIdx.x, lane = tid & 63, wid = tid >> 6;
  int b = blockIdx.y, c = blockIdx.x;
  int s_beg = c * 1024;
  int s_end = (c == NS - 1) ? ST : s_beg + 1024;
  int nsteps = (s_end - s_beg + 63) >> 6;
  int lm = lane & 15, lg = lane >> 4;

  short8 qf[2][4];                      // Q a-frags: [mf][kstep]
#pragma unroll
  for (int mf = 0; mf < 2; ++mf) {
    int qrow = wid * 32 + mf * 16 + lm;
    int h = qrow >> 4, t = qrow & 15;
    const ushort* qp = Y + (size_t)(b * TT + t) * 2304 + h * HD;
#pragma unroll
    for (int ks = 0; ks < 4; ++ks)
      qf[mf][ks] = *(const short8*)(qp + ks * 32 + lg * 8);
  }

  f32x4 o[2][8];
  float mrun[2][4], lrun[2][4];
#pragma unroll
  for (int mf = 0; mf < 2; ++mf) {
#pragma unroll
    for (int nf = 0; nf < 8; ++nf) o[mf][nf] = (f32x4){0.f, 0.f, 0.f, 0.f};
#pragma unroll
    for (int r = 0; r < 4; ++r) { mrun[mf][r] = -1e30f; lrun[mf][r] = 0.f; }
  }

  for (int st = 0; st < nsteps; ++st) {
    int s0 = s_beg + st * 64;
    // ---- stage K tile [64][128] fp32->bf16 (rows >= 8192 come from Y)
#pragma unroll
    for (int p = 0; p < 4; ++p) {
      int idx = p * 512 + tid;
      int sr = idx >> 5, g4 = idx & 31;
      int s = s0 + sr;
      ushort4 kb4;
      if (s < SC) {
        float4 f = *(const float4*)(Kc + ((size_t)b * SC + s) * HD + g4 * 4);
        kb4.x = f2bf(f.x); kb4.y = f2bf(f.y); kb4.z = f2bf(f.z); kb4.w = f2bf(f.w);
      } else if (s < ST) {
        kb4 = *(const ushort4*)(Y + (size_t)(b * TT + (s - SC)) * 2304 + EMB + g4 * 4);
      } else { kb4.x = kb4.y = kb4.z = kb4.w = 0; }
      *(ushort4*)&Klds[sr * 136 + g4 * 4] = kb4;
    }
    // ---- stage V transposed [d][s] via 4x4 blocks
    {
      int sb = tid >> 5, db = tid & 31;
      int r0 = sb * 4, d0 = db * 4;
      ushort v0[4], v1[4], v2[4], v3[4];
#pragma unroll
      for (int i = 0; i < 4; ++i) {
        int s = s0 + r0 + i;
        if (s < SC) {
          float4 f = *(const float4*)(Vc + ((size_t)b * SC + s) * HD + d0);
          v0[i] = f2bf(f.x); v1[i] = f2bf(f.y); v2[i] = f2bf(f.z); v3[i] = f2bf(f.w);
        } else if (s < ST) {
          ushort4 t4 = *(const ushort4*)(Y + (size_t)(b * TT + (s - SC)) * 2304 + EMB + HD + d0);
          v0[i] = t4.x; v1[i] = t4.y; v2[i] = t4.z; v3[i] = t4.w;
        } else { v0[i] = v1[i] = v2[i] = v3[i] = 0; }
      }
      ushort4 w;
      w.x = v0[0]; w.y = v0[1]; w.z = v0[2]; w.w = v0[3]; *(ushort4*)&Vt[(d0 + 0) * 72 + r0] = w;
      w.x = v1[0]; w.y = v1[1]; w.z = v1[2]; w.w = v1[3]; *(ushort4*)&Vt[(d0 + 1) * 72 + r0] = w;
      w.x = v2[0]; w.y = v2[1]; w.z = v2[2]; w.w = v2[3]; *(ushort4*)&Vt[(d0 + 2) * 72 + r0] = w;
      w.x = v3[0]; w.y = v3[1]; w.z = v3[2]; w.w = v3[3]; *(ushort4*)&Vt[(d0 + 3) * 72 + r0] = w;
    }
    __syncthreads();

    // ---- QK^T : [32 x 64] logits per wave
    f32x4 sacc[2][4];
#pragma unroll
    for (int mf = 0; mf < 2; ++mf)
#pragma unroll
      for (int nf = 0; nf < 4; ++nf) sacc[mf][nf] = (f32x4){0.f, 0.f, 0.f, 0.f};
#pragma unroll
    for (int kk = 0; kk < 4; ++kk) {
      short8 kf[4];
#pragma unroll
      for (int nf = 0; nf < 4; ++nf)
        kf[nf] = *(const short8*)&Klds[(nf * 16 + lm) * 136 + kk * 32 + lg * 8];
#pragma unroll
      for (int mf = 0; mf < 2; ++mf)
#pragma unroll
        for (int nf = 0; nf < 4; ++nf)
          sacc[mf][nf] = __builtin_amdgcn_mfma_f32_16x16x32_bf16(qf[mf][kk], kf[nf], sacc[mf][nf], 0, 0, 0);
    }

    // ---- mask tail cols
    if (s0 + 64 > s_end) {
#pragma unroll
      for (int nf = 0; nf < 4; ++nf) {
        int scol = s0 + nf * 16 + lm;
        if (scol >= s_end) {
#pragma unroll
          for (int mf = 0; mf < 2; ++mf)
#pragma unroll
            for (int r = 0; r < 4; ++r) sacc[mf][nf][r] = -1e30f;
        }
      }
    }

    // ---- online softmax (row = q), reduce across the 16 col-lanes
#pragma unroll
    for (int mf = 0; mf < 2; ++mf)
#pragma unroll
      for (int r = 0; r < 4; ++r) {
        float mx = fmaxf(fmaxf(sacc[mf][0][r], sacc[mf][1][r]),
                         fmaxf(sacc[mf][2][r], sacc[mf][3][r]));
#pragma unroll
        for (int m = 1; m <= 8; m <<= 1) mx = fmaxf(mx, __shfl_xor(mx, m, 64));
        float mn = fmaxf(mrun[mf][r], mx);
        float scl = __expf(mrun[mf][r] - mn);
        mrun[mf][r] = mn;
        float rs = 0.f;
#pragma unroll
        for (int nf = 0; nf < 4; ++nf) {
          float p = __expf(sacc[mf][nf][r] - mn);
          sacc[mf][nf][r] = p;
          rs += p;
        }
#pragma unroll
        for (int m = 1; m <= 8; m <<= 1) rs += __shfl_xor(rs, m, 64);
        lrun[mf][r] = lrun[mf][r] * scl + rs;
#pragma unroll
        for (int nf = 0; nf < 8; ++nf) o[mf][nf][r] *= scl;
      }

    // ---- P (C-layout) -> LDS -> A-frags ; PV in two 32-wide k halves
    ushort* pl = Plds[wid];
#pragma unroll
    for (int kh = 0; kh < 2; ++kh) {
#pragma unroll
      for (int mf = 0; mf < 2; ++mf)
#pragma unroll
        for (int nfh = 0; nfh < 2; ++nfh)
#pragma unroll
          for (int r = 0; r < 4; ++r)
            pl[(mf * 16 + lg * 4 + r) * 40 + nfh * 16 + lm] = f2bf(sacc[mf][kh * 2 + nfh][r]);
      short8 pa[2];
#pragma unroll
      for (int mf = 0; mf < 2; ++mf)
        pa[mf] = *(const short8*)&pl[(mf * 16 + lm) * 40 + lg * 8];
#pragma unroll
      for (int nf = 0; nf < 8; ++nf) {
        short8 vb = *(const short8*)&Vt[(nf * 16 + lm) * 72 + kh * 32 + lg * 8];
#pragma unroll
        for (int mf = 0; mf < 2; ++mf)
          o[mf][nf] = __builtin_amdgcn_mfma_f32_16x16x32_bf16(pa[mf], vb, o[mf][nf], 0, 0, 0);
      }
    }
    __syncthreads();
  }

  // ---- write chunk partials: O [b][c][256][128], (m,l) [b][c][256][2]
  float* op = Op + (size_t)(b * NS + c) * 256 * HD;
#pragma unroll
  for (int mf = 0; mf < 2; ++mf)
#pragma unroll
    for (int nf = 0; nf < 8; ++nf)
#pragma unroll
      for (int r = 0; r < 4; ++r) {
        int row = wid * 32 + mf * 16 + lg * 4 + r;
        op[(size_t)row * HD + nf * 16 + lm] = o[mf][nf][r];
      }
  if (lm == 0) {
    float* ml = ML + (size_t)(b * NS + c) * 256 * 2;
#pragma unroll
    for (int mf = 0; mf < 2; ++mf)
#pragma unroll
      for (int r = 0; r < 4; ++r) {
        int row = wid * 32 + mf * 16 + lg * 4 + r;
        ml[row * 2] = mrun[mf][r];
        ml[row * 2 + 1] = lrun[mf][r];
      }
  }
}

// ---------------------------------------------------------------- reduce chunks
__global__ __launch_bounds__(256) void attn_reduce(
    const float* __restrict__ Op, const float* __restrict__ ML,
    ushort* __restrict__ abf) {
  int e = blockIdx.x * 256 + threadIdx.x;   // grid covers exactly 32*256*128
  int d = e & 127;
  int r = (e >> 7) & 255;
  int b = e >> 15;
  const float* mlb = ML + (size_t)b * NS * 256 * 2;
  float mv[NS], lv[NS];
  float ms = -1e30f;
#pragma unroll
  for (int c = 0; c < NS; ++c) {
    mv[c] = mlb[(c * 256 + r) * 2];
    lv[c] = mlb[(c * 256 + r) * 2 + 1];
    ms = fmaxf(ms, mv[c]);
  }
  float Ov = 0.f, L = 0.f;
#pragma unroll
  for (int c = 0; c < NS; ++c) {
    float w = __expf(mv[c] - ms);
    L += w * lv[c];
    Ov += w * Op[(((size_t)b * NS + c) * 256 + r) * HD + d];
  }
  float outv = Ov / L;
  int h = r >> 4, t = r & 15;
  abf[(size_t)(b * TT + t) * EMB + h * HD + d] = f2bf(outv);
}

// ---------------------------------------------------------------- launch
extern "C" void kernel_launch(void* const* d_in, const int* in_sizes, int n_in,
                              void* d_out, int out_size, void* d_ws, size_t ws_size,
                              hipStream_t stream) {
  (void)in_sizes; (void)n_in; (void)out_size; (void)ws_size;
  const float* x  = (const float*)d_in[0];
  const float* Kc = (const float*)d_in[1];
  const float* Vc = (const float*)d_in[2];
  const float* Wq = (const float*)d_in[3];
  const float* bq = (const float*)d_in[4];
  const float* Wk = (const float*)d_in[5];
  const float* bk = (const float*)d_in[6];
  const float* Wv = (const float*)d_in[7];
  const float* bv = (const float*)d_in[8];
  const float* Wo = (const float*)d_in[9];
  const float* bo = (const float*)d_in[10];
  float* out = (float*)d_out;
  char* ws = (char*)d_ws;
  // ws layout (bytes, 256-aligned), total ~58.5 MB
  ushort* xbf   = (ushort*)(ws);                  //  2,097,152  x bf16 [512][2048]
  ushort* wqkv  = (ushort*)(ws + 2097152);        //  9,437,184  [2304][2048]
  ushort* wobf  = (ushort*)(ws + 11534336);       //  8,388,608  [2048][2048]
  ushort* ybf   = (ushort*)(ws + 19922944);       //  2,359,296  Y [512][2304]
  float*  biasq = (float*) (ws + 22282240);       //      9,216  bias concat
  float*  Opart = (float*) (ws + 22291456);       // 33,554,432  [32][8][256][128]
  float*  MLp   = (float*) (ws + 55845888);       //    524,288  [32][8][256][2]
  ushort* abf   = (ushort*)(ws + 56370176);       //  2,097,152  attn out bf16

  prepack<<<2048, 256, 0, stream>>>(x, Wq, Wk, Wv, Wo, bq, bk, bv, xbf, wqkv, wobf, biasq);
  // QKV projection: Y = x @ [Wq;Wk;Wv]^T + bias, Q cols pre-scaled by 1/sqrt(128)
  gemm_bt<<<144, 256, 0, stream>>>(xbf, wqkv, biasq, nullptr, ybf, 2304, 2048, QK_SCALE, 2048);
  attn_part<<<dim3(NS, BB), 512, 0, stream>>>(Kc, Vc, ybf, Opart, MLp);
  attn_reduce<<<4096, 256, 0, stream>>>(Opart, MLp, abf);
  // output projection: out = attn @ Wo^T + bo (fp32 out)
  gemm_bt<<<128, 256, 0, stream>>>(abf, wobf, bo, out, nullptr, 2048, 2048, 1.0f, 0);
}

// Round 4
// 456.561 us; speedup vs baseline: 1.0330x; 1.0330x over previous
//
#include <hip/hip_runtime.h>
#include <cstdint>

#define EMB 2048
#define NH 16
#define HD 128
#define BB 32
#define TT 16
#define SC 8192
#define ST 8208
#define NS 8
#define QK_SCALE 0.08838834764831845f

typedef __attribute__((ext_vector_type(8))) short short8;
typedef __attribute__((ext_vector_type(4))) float f32x4;

__device__ __forceinline__ ushort f2bf(float f) {
  union { float f; uint32_t u; } v; v.f = f;
  uint32_t u = v.u;
  return (ushort)((u + 0x7FFFu + ((u >> 16) & 1u)) >> 16);
}

// async global->LDS, 16B per lane; LDS dest = wave-uniform base + lane*16
typedef __attribute__((address_space(1))) void gas_t;
typedef __attribute__((address_space(3))) void las_t;
__device__ __forceinline__ void gload16(const void* g, void* l) {
  __builtin_amdgcn_global_load_lds((gas_t*)g, (las_t*)l, 16, 0, 0);
}

// barrier that waits ONLY lgkm (LDS) — leaves register global-loads in flight.
__device__ __forceinline__ void bar_lgkm() {
  asm volatile("s_waitcnt lgkmcnt(0)" ::: "memory");
  __builtin_amdgcn_sched_barrier(0);
  __builtin_amdgcn_s_barrier();
  __builtin_amdgcn_sched_barrier(0);
}

// ---------------------------------------------------------------- prepack
__global__ __launch_bounds__(256) void prepack(
    const float* __restrict__ x, const float* __restrict__ Wq,
    const float* __restrict__ Wk, const float* __restrict__ Wv,
    const float* __restrict__ Wo, const float* __restrict__ bq,
    const float* __restrict__ bk, const float* __restrict__ bv,
    ushort* __restrict__ xbf, ushort* __restrict__ wqkv,
    ushort* __restrict__ wobf, float* __restrict__ biasq) {
  const int B0 = 262144;            // x float4s
  const int B1 = B0 + 1048576;      // Wq
  const int B2 = B1 + 65536;        // Wk
  const int B3 = B2 + 65536;        // Wv
  const int B4 = B3 + 1048576;      // Wo
  const int B5 = B4 + 576;          // bias
  int stride = gridDim.x * blockDim.x;
  for (int i = blockIdx.x * blockDim.x + threadIdx.x; i < B5; i += stride) {
    const float* src; ushort* dst;
    if (i < B0)      { src = x  + (size_t)i * 4;        dst = xbf  + (size_t)i * 4; }
    else if (i < B1) { src = Wq + (size_t)(i - B0) * 4; dst = wqkv + (size_t)(i - B0) * 4; }
    else if (i < B2) { src = Wk + (size_t)(i - B1) * 4; dst = wqkv + 4194304 + (size_t)(i - B1) * 4; }
    else if (i < B3) { src = Wv + (size_t)(i - B2) * 4; dst = wqkv + 4456448 + (size_t)(i - B2) * 4; }
    else if (i < B4) { src = Wo + (size_t)(i - B3) * 4; dst = wobf + (size_t)(i - B3) * 4; }
    else {
      int j = i - B4;
      const float* bs = (j < 512) ? bq + j * 4 : (j < 544) ? bk + (j - 512) * 4 : bv + (j - 544) * 4;
      float4 f = *(const float4*)bs;
      *(float4*)(biasq + j * 4) = f;
      continue;
    }
    float4 f = *(const float4*)src;
    ushort4 o4;
    o4.x = f2bf(f.x); o4.y = f2bf(f.y); o4.z = f2bf(f.z); o4.w = f2bf(f.w);
    *(ushort4*)dst = o4;
  }
}

// ---------------------------------------------------------------- GEMM (NT)
// C[M,N] = A[M,K]*B[N,K]^T + bias. BM=BN=BK=64, 4 waves (2x2, wave 32x32).
// 2-phase ping-pong: STAGE(next tile) -> compute(cur) -> __syncthreads()
// (whose vmcnt(0) drain is exactly the per-tile wait). M = 512 (8 m-tiles).
__global__ __launch_bounds__(256) void gemm_bt(
    const ushort* __restrict__ A, const ushort* __restrict__ B,
    const float* __restrict__ bias, float* __restrict__ outF,
    ushort* __restrict__ outB, int N, int K, float scale, int scaleLim) {
  __shared__ ushort As[2][64 * 64];
  __shared__ ushort Bs[2][64 * 64];
  int tid = threadIdx.x, lane = tid & 63, wid = tid >> 6;
  int wm = wid >> 1, wn = wid & 1;
  int nwg = gridDim.x, bid = blockIdx.x;
  int sw = (bid & 7) * (nwg >> 3) + (bid >> 3);   // bijective XCD swizzle (nwg%8==0)
  int mt = sw & 7, nt = sw >> 3;                  // consecutive sw share B panel
  int m0 = mt * 64, n0 = nt * 64;
  int lrow = lane >> 3;                           // 0..7 within chunk
  int gg0 = (lane & 7) ^ (lrow & 7);              // source col-block swizzle

  f32x4 acc[2][2];
#pragma unroll
  for (int mf = 0; mf < 2; ++mf)
#pragma unroll
    for (int nf = 0; nf < 2; ++nf) acc[mf][nf] = (f32x4){0.f, 0.f, 0.f, 0.f};

  const int KT = K >> 6;
  auto stage = [&](int buf, int kt) {
    int kb = kt * 64;
#pragma unroll
    for (int p = 0; p < 4; ++p) {                 // 16 chunks of 1KB, 4/wave
      int c = wid * 4 + p;
      int ca = c & 7;
      int row = ca * 8 + lrow;
      const ushort* src = (c < 8) ? A + (size_t)(m0 + row) * K + kb + gg0 * 8
                                  : B + (size_t)(n0 + row) * K + kb + gg0 * 8;
      ushort* dst = (c < 8) ? &As[buf][ca * 512] : &Bs[buf][ca * 512];
      gload16(src, dst);
    }
  };

  stage(0, 0);
  __syncthreads();
  for (int kt = 0; kt < KT; ++kt) {
    int cur = kt & 1;
    if (kt + 1 < KT) stage(cur ^ 1, kt + 1);
#pragma unroll
    for (int kk = 0; kk < 2; ++kk) {
      short8 af[2], bf2[2];
#pragma unroll
      for (int mf = 0; mf < 2; ++mf) {
        int r = wm * 32 + mf * 16 + (lane & 15);
        int gg = (kk * 4 + (lane >> 4)) ^ (r & 7);
        af[mf] = *(const short8*)&As[cur][r * 64 + gg * 8];
      }
#pragma unroll
      for (int nf = 0; nf < 2; ++nf) {
        int r = wn * 32 + nf * 16 + (lane & 15);
        int gg = (kk * 4 + (lane >> 4)) ^ (r & 7);
        bf2[nf] = *(const short8*)&Bs[cur][r * 64 + gg * 8];
      }
#pragma unroll
      for (int mf = 0; mf < 2; ++mf)
#pragma unroll
        for (int nf = 0; nf < 2; ++nf)
          acc[mf][nf] = __builtin_amdgcn_mfma_f32_16x16x32_bf16(af[mf], bf2[nf], acc[mf][nf], 0, 0, 0);
    }
    __syncthreads();                              // drains vmcnt(0): next tile ready
  }
#pragma unroll
  for (int mf = 0; mf < 2; ++mf)
#pragma unroll
    for (int nf = 0; nf < 2; ++nf)
#pragma unroll
      for (int r = 0; r < 4; ++r) {
        int gr = m0 + wm * 32 + mf * 16 + (lane >> 4) * 4 + r;
        int gc = n0 + wn * 32 + nf * 16 + (lane & 15);
        float v = acc[mf][nf][r] + bias[gc];
        if (gc < scaleLim) v *= scale;
        if (outB) outB[(size_t)gr * N + gc] = f2bf(v);
        else      outF[(size_t)gr * N + gc] = v;
      }
}

// ---------------------------------------------------------------- attention partials
// grid (NS, B); block 512 = 8 waves, wave owns 32 q-rows (row = h*16+t).
// T14 async-STAGE: register-prefetch next 64-row K/V tile while computing
// current; lgkm-only barriers keep the loads in flight across s_barrier.
__global__ __launch_bounds__(512) void attn_part(
    const float* __restrict__ Kc, const float* __restrict__ Vc,
    const ushort* __restrict__ Y, float* __restrict__ Op, float* __restrict__ ML) {
  __shared__ ushort Klds[64 * 136];     // [s][k] pad 8
  __shared__ ushort Vt[128 * 64];       // [d][s], s-offset XOR-swizzled by ((d>>2)&7)<<3
  __shared__ ushort Plds[8][32 * 40];   // per-wave P half-tile
  int tid = threadIdx.x, lane = tid & 63, wid = tid >> 6;
  int b = blockIdx.y, c = blockIdx.x;
  int s_beg = c * 1024;
  int lm = lane & 15, lg = lane >> 4;
  int krow = tid >> 5, kcol = tid & 31;           // K load mapping
  int db = tid & 31, sb = tid >> 5;               // V load mapping
  int d0 = db * 4, r0 = sb * 4;
  int vswz = (db & 7) << 3;                       // ushort-units swizzle for V writes

  short8 qf[2][4];
#pragma unroll
  for (int mf = 0; mf < 2; ++mf) {
    int qrow = wid * 32 + mf * 16 + lm;
    int h = qrow >> 4, t = qrow & 15;
    const ushort* qp = Y + (size_t)(b * TT + t) * 2304 + h * HD;
#pragma unroll
    for (int ks = 0; ks < 4; ++ks)
      qf[mf][ks] = *(const short8*)(qp + ks * 32 + lg * 8);
  }

  f32x4 o[2][8];
  float mrun[2][4], lrun[2][4];
#pragma unroll
  for (int mf = 0; mf < 2; ++mf) {
#pragma unroll
    for (int nf = 0; nf < 8; ++nf) o[mf][nf] = (f32x4){0.f, 0.f, 0.f, 0.f};
#pragma unroll
    for (int r = 0; r < 4; ++r) { mrun[mf][r] = -1e30f; lrun[mf][r] = 0.f; }
  }

  const float4* K4 = (const float4*)Kc;
  const float4* V4 = (const float4*)Vc;
  size_t base4 = (size_t)b * SC * 32;             // float4 units

  auto LOAD = [&](float4 (&kr)[4], float4 (&vr)[4], int s0) {
#pragma unroll
    for (int p = 0; p < 4; ++p)
      kr[p] = K4[base4 + (size_t)(s0 + p * 16 + krow) * 32 + kcol];
#pragma unroll
    for (int i = 0; i < 4; ++i)
      vr[i] = V4[base4 + (size_t)(s0 + r0 + i) * 32 + db];
  };
  auto STAGE = [&](const float4 (&kr)[4], const float4 (&vr)[4]) {
#pragma unroll
    for (int p = 0; p < 4; ++p) {
      ushort4 u;
      u.x = f2bf(kr[p].x); u.y = f2bf(kr[p].y); u.z = f2bf(kr[p].z); u.w = f2bf(kr[p].w);
      *(ushort4*)&Klds[(p * 16 + krow) * 136 + kcol * 4] = u;
    }
    ushort4 w;
    w.x = f2bf(vr[0].x); w.y = f2bf(vr[1].x); w.z = f2bf(vr[2].x); w.w = f2bf(vr[3].x);
    *(ushort4*)&Vt[(d0 + 0) * 64 + (r0 ^ vswz)] = w;
    w.x = f2bf(vr[0].y); w.y = f2bf(vr[1].y); w.z = f2bf(vr[2].y); w.w = f2bf(vr[3].y);
    *(ushort4*)&Vt[(d0 + 1) * 64 + (r0 ^ vswz)] = w;
    w.x = f2bf(vr[0].z); w.y = f2bf(vr[1].z); w.z = f2bf(vr[2].z); w.w = f2bf(vr[3].z);
    *(ushort4*)&Vt[(d0 + 2) * 64 + (r0 ^ vswz)] = w;
    w.x = f2bf(vr[0].w); w.y = f2bf(vr[1].w); w.z = f2bf(vr[2].w); w.w = f2bf(vr[3].w);
    *(ushort4*)&Vt[(d0 + 3) * 64 + (r0 ^ vswz)] = w;
  };

  auto COMPUTE = [&](int s0, int send) {
    f32x4 sacc[2][4];
#pragma unroll
    for (int mf = 0; mf < 2; ++mf)
#pragma unroll
      for (int nf = 0; nf < 4; ++nf) sacc[mf][nf] = (f32x4){0.f, 0.f, 0.f, 0.f};
#pragma unroll
    for (int kk = 0; kk < 4; ++kk) {
      short8 kf[4];
#pragma unroll
      for (int nf = 0; nf < 4; ++nf)
        kf[nf] = *(const short8*)&Klds[(nf * 16 + lm) * 136 + kk * 32 + lg * 8];
      __builtin_amdgcn_s_setprio(1);
#pragma unroll
      for (int mf = 0; mf < 2; ++mf)
#pragma unroll
        for (int nf = 0; nf < 4; ++nf)
          sacc[mf][nf] = __builtin_amdgcn_mfma_f32_16x16x32_bf16(qf[mf][kk], kf[nf], sacc[mf][nf], 0, 0, 0);
      __builtin_amdgcn_s_setprio(0);
    }
    if (s0 + 64 > send) {
#pragma unroll
      for (int nf = 0; nf < 4; ++nf) {
        int scol = s0 + nf * 16 + lm;
        if (scol >= send) {
#pragma unroll
          for (int mf = 0; mf < 2; ++mf)
#pragma unroll
            for (int r = 0; r < 4; ++r) sacc[mf][nf][r] = -1e30f;
        }
      }
    }
#pragma unroll
    for (int mf = 0; mf < 2; ++mf)
#pragma unroll
      for (int r = 0; r < 4; ++r) {
        float mx = fmaxf(fmaxf(sacc[mf][0][r], sacc[mf][1][r]),
                         fmaxf(sacc[mf][2][r], sacc[mf][3][r]));
#pragma unroll
        for (int m = 1; m <= 8; m <<= 1) mx = fmaxf(mx, __shfl_xor(mx, m, 64));
        float mn = fmaxf(mrun[mf][r], mx);
        float scl = __expf(mrun[mf][r] - mn);
        mrun[mf][r] = mn;
        float rs = 0.f;
#pragma unroll
        for (int nf = 0; nf < 4; ++nf) {
          float p = __expf(sacc[mf][nf][r] - mn);
          sacc[mf][nf][r] = p;
          rs += p;
        }
#pragma unroll
        for (int m = 1; m <= 8; m <<= 1) rs += __shfl_xor(rs, m, 64);
        lrun[mf][r] = lrun[mf][r] * scl + rs;
#pragma unroll
        for (int nf = 0; nf < 8; ++nf) o[mf][nf][r] *= scl;
      }
    ushort* pl = Plds[wid];
#pragma unroll
    for (int kh = 0; kh < 2; ++kh) {
#pragma unroll
      for (int mf = 0; mf < 2; ++mf)
#pragma unroll
        for (int nfh = 0; nfh < 2; ++nfh)
#pragma unroll
          for (int r = 0; r < 4; ++r)
            pl[(mf * 16 + lg * 4 + r) * 40 + nfh * 16 + lm] = f2bf(sacc[mf][kh * 2 + nfh][r]);
      short8 pa[2];
#pragma unroll
      for (int mf = 0; mf < 2; ++mf)
        pa[mf] = *(const short8*)&pl[(mf * 16 + lm) * 40 + lg * 8];
#pragma unroll
      for (int nf = 0; nf < 8; ++nf) {
        int row = nf * 16 + lm;
        int soff = (kh * 32 + lg * 8) ^ (((row >> 2) & 7) << 3);
        short8 vb = *(const short8*)&Vt[row * 64 + soff];
        __builtin_amdgcn_s_setprio(1);
#pragma unroll
        for (int mf = 0; mf < 2; ++mf)
          o[mf][nf] = __builtin_amdgcn_mfma_f32_16x16x32_bf16(pa[mf], vb, o[mf][nf], 0, 0, 0);
        __builtin_amdgcn_s_setprio(0);
      }
    }
  };

  float4 kA[4], vA[4], kB[4], vB[4];
  LOAD(kA, vA, s_beg);
  for (int st = 0; st < 16; st += 2) {
    int s1 = s_beg + (st + 1) * 64;
    LOAD(kB, vB, s1);                   // prefetch st+1 (always < 16 here)
    STAGE(kA, vA);
    bar_lgkm();
    COMPUTE(s_beg + st * 64, ST);
    bar_lgkm();
    if (st + 2 < 16) LOAD(kA, vA, s_beg + (st + 2) * 64);
    STAGE(kB, vB);
    bar_lgkm();
    COMPUTE(s1, ST);
    bar_lgkm();
  }

  // Y-sourced tail step (new tokens, s = 8192..8207) — only last chunk
  if (c == NS - 1) {
    int s0 = SC;
#pragma unroll
    for (int p = 0; p < 4; ++p) {
      int sr = p * 16 + krow;
      ushort4 u;
      if (sr < TT) u = *(const ushort4*)(Y + (size_t)(b * TT + sr) * 2304 + EMB + kcol * 4);
      else { u.x = u.y = u.z = u.w = 0; }
      *(ushort4*)&Klds[sr * 136 + kcol * 4] = u;
    }
    {
      ushort v0[4], v1[4], v2[4], v3[4];
#pragma unroll
      for (int i = 0; i < 4; ++i) {
        int sl = r0 + i;
        if (sl < TT) {
          ushort4 t4 = *(const ushort4*)(Y + (size_t)(b * TT + sl) * 2304 + EMB + HD + d0);
          v0[i] = t4.x; v1[i] = t4.y; v2[i] = t4.z; v3[i] = t4.w;
        } else { v0[i] = v1[i] = v2[i] = v3[i] = 0; }
      }
      ushort4 w;
      w.x = v0[0]; w.y = v0[1]; w.z = v0[2]; w.w = v0[3]; *(ushort4*)&Vt[(d0 + 0) * 64 + (r0 ^ vswz)] = w;
      w.x = v1[0]; w.y = v1[1]; w.z = v1[2]; w.w = v1[3]; *(ushort4*)&Vt[(d0 + 1) * 64 + (r0 ^ vswz)] = w;
      w.x = v2[0]; w.y = v2[1]; w.z = v2[2]; w.w = v2[3]; *(ushort4*)&Vt[(d0 + 2) * 64 + (r0 ^ vswz)] = w;
      w.x = v3[0]; w.y = v3[1]; w.z = v3[2]; w.w = v3[3]; *(ushort4*)&Vt[(d0 + 3) * 64 + (r0 ^ vswz)] = w;
    }
    bar_lgkm();
    COMPUTE(s0, ST);
  }

  float* op = Op + (size_t)(b * NS + c) * 256 * HD;
#pragma unroll
  for (int mf = 0; mf < 2; ++mf)
#pragma unroll
    for (int nf = 0; nf < 8; ++nf)
#pragma unroll
      for (int r = 0; r < 4; ++r) {
        int row = wid * 32 + mf * 16 + lg * 4 + r;
        op[(size_t)row * HD + nf * 16 + lm] = o[mf][nf][r];
      }
  if (lm == 0) {
    float* ml = ML + (size_t)(b * NS + c) * 256 * 2;
#pragma unroll
    for (int mf = 0; mf < 2; ++mf)
#pragma unroll
      for (int r = 0; r < 4; ++r) {
        int row = wid * 32 + mf * 16 + lg * 4 + r;
        ml[row * 2] = mrun[mf][r];
        ml[row * 2 + 1] = lrun[mf][r];
      }
  }
}

// ---------------------------------------------------------------- reduce chunks
__global__ __launch_bounds__(256) void attn_reduce(
    const float* __restrict__ Op, const float* __restrict__ ML,
    ushort* __restrict__ abf) {
  int e = blockIdx.x * 256 + threadIdx.x;
  int d = e & 127;
  int r = (e >> 7) & 255;
  int b = e >> 15;
  const float* mlb = ML + (size_t)b * NS * 256 * 2;
  float mv[NS], lv[NS];
  float ms = -1e30f;
#pragma unroll
  for (int c = 0; c < NS; ++c) {
    mv[c] = mlb[(c * 256 + r) * 2];
    lv[c] = mlb[(c * 256 + r) * 2 + 1];
    ms = fmaxf(ms, mv[c]);
  }
  float Ov = 0.f, L = 0.f;
#pragma unroll
  for (int c = 0; c < NS; ++c) {
    float w = __expf(mv[c] - ms);
    L += w * lv[c];
    Ov += w * Op[(((size_t)b * NS + c) * 256 + r) * HD + d];
  }
  float outv = Ov / L;
  int h = r >> 4, t = r & 15;
  abf[(size_t)(b * TT + t) * EMB + h * HD + d] = f2bf(outv);
}

// ---------------------------------------------------------------- launch
extern "C" void kernel_launch(void* const* d_in, const int* in_sizes, int n_in,
                              void* d_out, int out_size, void* d_ws, size_t ws_size,
                              hipStream_t stream) {
  (void)in_sizes; (void)n_in; (void)out_size; (void)ws_size;
  const float* x  = (const float*)d_in[0];
  const float* Kc = (const float*)d_in[1];
  const float* Vc = (const float*)d_in[2];
  const float* Wq = (const float*)d_in[3];
  const float* bq = (const float*)d_in[4];
  const float* Wk = (const float*)d_in[5];
  const float* bk = (const float*)d_in[6];
  const float* Wv = (const float*)d_in[7];
  const float* bv = (const float*)d_in[8];
  const float* Wo = (const float*)d_in[9];
  const float* bo = (const float*)d_in[10];
  float* out = (float*)d_out;
  char* ws = (char*)d_ws;
  ushort* xbf   = (ushort*)(ws);                  //  2,097,152  x bf16 [512][2048]
  ushort* wqkv  = (ushort*)(ws + 2097152);        //  9,437,184  [2304][2048]
  ushort* wobf  = (ushort*)(ws + 11534336);       //  8,388,608  [2048][2048]
  ushort* ybf   = (ushort*)(ws + 19922944);       //  2,359,296  Y [512][2304]
  float*  biasq = (float*) (ws + 22282240);       //      9,216  bias concat
  float*  Opart = (float*) (ws + 22291456);       // 33,554,432  [32][8][256][128]
  float*  MLp   = (float*) (ws + 55845888);       //    524,288  [32][8][256][2]
  ushort* abf   = (ushort*)(ws + 56370176);       //  2,097,152  attn out bf16

  prepack<<<2048, 256, 0, stream>>>(x, Wq, Wk, Wv, Wo, bq, bk, bv, xbf, wqkv, wobf, biasq);
  gemm_bt<<<288, 256, 0, stream>>>(xbf, wqkv, biasq, nullptr, ybf, 2304, 2048, QK_SCALE, 2048);
  attn_part<<<dim3(NS, BB), 512, 0, stream>>>(Kc, Vc, ybf, Opart, MLp);
  attn_reduce<<<4096, 256, 0, stream>>>(Opart, MLp, abf);
  gemm_bt<<<256, 256, 0, stream>>>(abf, wobf, bo, out, nullptr, 2048, 2048, 1.0f, 0);
}